// Round 13
// baseline (1789.948 us; speedup 1.0000x reference)
//
#include <hip/hip_runtime.h>
#include <hip/hip_bf16.h>
#include <math.h>

#define HDIM 256

typedef unsigned short u16;
typedef short short8 __attribute__((ext_vector_type(8)));
typedef _Float16 f16x8 __attribute__((ext_vector_type(8)));
typedef float f32x4 __attribute__((ext_vector_type(4)));

// branch-free shifted softplus
__device__ __forceinline__ float sspf(float x) {
  const float LOG2E = 1.4426950408889634f, LN2 = 0.6931471805599453f;
  float t = exp2f(-fabsf(x) * LOG2E);
  return fmaxf(x, 0.f) + (log2f(1.f + t) - 1.f) * LN2;
}
__device__ __forceinline__ float bf2f(u16 u) {
  union { unsigned int i; float f; } x; x.i = ((unsigned int)u) << 16; return x.f;
}
__device__ __forceinline__ u16 f2bf(float f) {
  union { float f; unsigned int i; } x; x.f = f;
  unsigned int r = x.i + 0x7FFFu + ((x.i >> 16) & 1u);
  return (u16)(r >> 16);
}
__device__ __forceinline__ u16 f2h_bits(float f) {
  _Float16 h = (_Float16)f;
  return __builtin_bit_cast(unsigned short, h);
}
__device__ __forceinline__ float4 ld4f(const float* p) { return *(const float4*)p; }

// XOR-swizzled inter buffer (64 rows x 256 u16, 32 KB)
__device__ __forceinline__ int iw_idx(int row, int col) {
  return row * 256 + ((((col >> 3) ^ (row & 7)) << 3) | (col & 7));
}
__device__ __forceinline__ int ir_idx(int row, int cchunk) {
  return row * 256 + ((cchunk ^ (row & 7)) << 3);
}

template<int DT>
__device__ __forceinline__ f32x4 mma(short8 a, short8 b, f32x4 c) {
  if constexpr (DT == 0)
    return __builtin_amdgcn_mfma_f32_16x16x32_bf16(a, b, c, 0, 0, 0);
  else
    return __builtin_amdgcn_mfma_f32_16x16x32_f16(__builtin_bit_cast(f16x8, a),
                                                  __builtin_bit_cast(f16x8, b), c, 0, 0, 0);
}

__device__ __forceinline__ void zacc(f32x4 (&acc)[4][4]) {
#pragma unroll
  for (int i = 0; i < 4; ++i)
#pragma unroll
    for (int j = 0; j < 4; ++j) { acc[i][j][0]=0.f; acc[i][j][1]=0.f; acc[i][j][2]=0.f; acc[i][j][3]=0.f; }
}

// GEMM: 64 rows x (NTW*16 cols per wave), A from swizzled inter LDS, B per-lane global
// (k-step-major bt: [kstep][n][32]). Barrier-free.
template<int NSTEPS, int BT_N, int NTW, int DT, bool WRAP8, typename ATR>
__device__ __forceinline__ void gemm44(f32x4 (&acc)[4][4], const u16* __restrict__ bt,
                                       const u16* __restrict__ inter,
                                       int w, int m, int quad, ATR atr) {
  short8 bf[2][NTW];
#pragma unroll
  for (int nt = 0; nt < NTW; ++nt)
    bf[0][nt] = *(const short8*)(bt + (w * (NTW * 16) + nt * 16 + m) * 32 + quad * 8);
#pragma unroll
  for (int ks = 0; ks < NSTEPS; ++ks) {
    const int cur = ks & 1, nxt = cur ^ 1;
    if (ks + 1 < NSTEPS) {
#pragma unroll
      for (int nt = 0; nt < NTW; ++nt)
        bf[nxt][nt] = *(const short8*)(bt + (size_t)(ks + 1) * (BT_N * 32)
                                       + (w * (NTW * 16) + nt * 16 + m) * 32 + quad * 8);
    }
    int kchunk = (WRAP8 ? (ks & 7) : ks) * 4 + quad;
#pragma unroll
    for (int mt = 0; mt < 4; ++mt) {
      short8 af = *(const short8*)&inter[ir_idx(mt * 16 + m, kchunk)];
      af = atr(mt, ks, af);
#pragma unroll
      for (int nt = 0; nt < NTW; ++nt)
        acc[mt][nt] = mma<DT>(af, bf[cur][nt], acc[mt][nt]);
    }
  }
}

// epilogue -> swizzled inter. ACT: 0 none 1 relu 2 ssp. OF: 0 bf16, 1 f16
template<int NTW, int ACT, int OF>
__device__ __forceinline__ void store_inter44(u16* inter, int w, int m, int quad,
                                              const f32x4 (&acc)[4][4], const float* bias) {
#pragma unroll
  for (int mt = 0; mt < 4; ++mt)
#pragma unroll
    for (int nt = 0; nt < NTW; ++nt) {
      int col = w * (NTW * 16) + nt * 16 + m;
      float bv = bias[col];
#pragma unroll
      for (int r = 0; r < 4; ++r) {
        int row = mt * 16 + quad * 4 + r;
        float x = acc[mt][nt][r] + bv;
        if (ACT == 1) x = fmaxf(x, 0.f);
        else if (ACT == 2) x = sspf(x);
        inter[iw_idx(row, col)] = (OF == 0) ? f2bf(x) : f2h_bits(x);
      }
    }
}

// coalesced non-temporal copy-out: swizzled inter -> global rows (streaming, no L2 fill)
__device__ __forceinline__ void copy_out_nt(u16* C, int row0, const u16* inter, int t) {
#pragma unroll
  for (int c = 0; c < 8; ++c) {
    int idx = c * 256 + t;
    int row = idx >> 5, c8 = idx & 31;
    int src = (c8 ^ (row & 7)) << 3;
    short8 v = *(const short8*)&inter[row * 256 + src];
    __builtin_nontemporal_store(v, (short8*)(C + (size_t)(row0 + row) * HDIM + c8 * 8));
  }
}

template<int NTW, int ACT, int CM>
__device__ __forceinline__ void store_node44(float* C, int row0, int w, int m, int quad,
                                             const f32x4 (&acc)[4][4], const float* bias, int M) {
#pragma unroll
  for (int mt = 0; mt < 4; ++mt)
#pragma unroll
    for (int nt = 0; nt < NTW; ++nt) {
      int col = w * (NTW * 16) + nt * 16 + m;
      float bv = bias ? bias[col] : 0.f;
#pragma unroll
      for (int r = 0; r < 4; ++r) {
        int row = row0 + mt * 16 + quad * 4 + r;
        if (row < M) {
          float x = acc[mt][nt][r] + bv;
          if (ACT == 2) x = sspf(x);
          size_t idx = (size_t)row * HDIM + col;
          if (CM == 1) x += C[idx];
          C[idx] = x;
        }
      }
    }
}

// ================= fused edge encoder =================
struct EncArgs {
  const int* se_e; const float* lenp; const float* W1; const float* b1;
  const u16* btA; const float* bA;
  const float* bondT; const int* etr; const int* etp;
  const u16* btB; const float* bB;
  const u16* btC; const float* bC;
  u16* outp;
};
__global__ __launch_bounds__(256, 3) void encoder_k(EncArgs a) {
  __shared__ u16 inter[64 * 256];
  __shared__ u16 bondL[24 * 264];
  const int t = threadIdx.x;
  const int w = t >> 6, lane = t & 63, m = lane & 15, quad = lane >> 4;
  const int row0 = blockIdx.x * 64;
  auto idt = [](int, int, short8 v) { return v; };

  for (int i = t; i < 24 * 256; i += 256) {
    int r = i >> 8, c = i & 255;
    bondL[r * 264 + c] = f2h_bits(a.bondT[r * 256 + c]);
  }
  int brv[4], bpv[4];
#pragma unroll
  for (int mt = 0; mt < 4; ++mt) {
    int eo = a.se_e[row0 + mt * 16 + m];
    brv[mt] = a.etr[eo]; bpv[mt] = a.etp[eo];
  }
  // pre-pass A: inter = ssp(len*W1+b1) bf16
  {
    int row = t >> 2;
    float len = a.lenp[a.se_e[row0 + row]];
#pragma unroll
    for (int c = 0; c < 8; ++c) {
      int chunk = (t & 3) + c * 4, k = chunk * 8;
      float4 w0 = ld4f(a.W1 + k), w1 = ld4f(a.W1 + k + 4);
      float4 c0 = ld4f(a.b1 + k), c1 = ld4f(a.b1 + k + 4);
      short8 v;
      v[0] = (short)f2bf(sspf(len * w0.x + c0.x)); v[1] = (short)f2bf(sspf(len * w0.y + c0.y));
      v[2] = (short)f2bf(sspf(len * w0.z + c0.z)); v[3] = (short)f2bf(sspf(len * w0.w + c0.w));
      v[4] = (short)f2bf(sspf(len * w1.x + c1.x)); v[5] = (short)f2bf(sspf(len * w1.y + c1.y));
      v[6] = (short)f2bf(sspf(len * w1.z + c1.z)); v[7] = (short)f2bf(sspf(len * w1.w + c1.w));
      *(short8*)&inter[row * 256 + ((chunk ^ (row & 7)) << 3)] = v;
    }
  }
  __syncthreads();
  f32x4 acc[4][4];
  zacc(acc);
  gemm44<8, 256, 4, 0, false>(acc, a.btA, inter, w, m, quad, idt);
  __syncthreads();
  store_inter44<4, 0, 1>(inter, w, m, quad, acc, a.bA);   // d_emb as f16
  __syncthreads();
  zacc(acc);
  auto atrB = [&](int mt, int ks, short8 v) -> short8 {
    int k2 = (ks & 7) * 32 + quad * 8;
    int et = (ks < 8) ? brv[mt] : bpv[mt];
    f16x8 dv = __builtin_bit_cast(f16x8, v);
    f16x8 bd = __builtin_bit_cast(f16x8, *(const short8*)&bondL[et * 264 + k2]);
    return __builtin_bit_cast(short8, dv * bd);
  };
  gemm44<16, 256, 4, 1, true>(acc, a.btB, inter, w, m, quad, atrB);
  __syncthreads();
  store_inter44<4, 1, 0>(inter, w, m, quad, acc, a.bB);   // relu, bf16
  __syncthreads();
  zacc(acc);
  gemm44<8, 256, 4, 0, false>(acc, a.btC, inter, w, m, quad, idt);
  __syncthreads();                                        // inter reads done
  store_inter44<4, 0, 0>(inter, w, m, quad, acc, a.bC);
  __syncthreads();
  copy_out_nt(a.outp, row0, inter, t);
}

// ================= fused filter net =================
struct FiltArgs { const u16* inA; const u16* bt1; const float* b1; const u16* bt2; const float* b2; u16* outp; };
__global__ __launch_bounds__(256, 3) void filt_k(FiltArgs a) {
  __shared__ u16 inter[64 * 256];
  const int t = threadIdx.x;
  const int w = t >> 6, lane = t & 63, m = lane & 15, quad = lane >> 4;
  const int row0 = blockIdx.x * 64;
  auto idt = [](int, int, short8 v) { return v; };
  {
    int row = t >> 2;
#pragma unroll
    for (int c = 0; c < 8; ++c) {
      int chunk = (t & 3) + c * 4;
      short8 v = __builtin_nontemporal_load((const short8*)(a.inA + (size_t)(row0 + row) * HDIM + chunk * 8));
      *(short8*)&inter[row * 256 + ((chunk ^ (row & 7)) << 3)] = v;
    }
  }
  __syncthreads();
  f32x4 acc[4][4];
  zacc(acc);
  gemm44<8, 256, 4, 0, false>(acc, a.bt1, inter, w, m, quad, idt);
  __syncthreads();
  store_inter44<4, 2, 0>(inter, w, m, quad, acc, a.b1);   // ssp
  __syncthreads();
  zacc(acc);
  gemm44<8, 256, 4, 0, false>(acc, a.bt2, inter, w, m, quad, idt);
  __syncthreads();
  store_inter44<4, 0, 0>(inter, w, m, quad, acc, a.b2);
  __syncthreads();
  copy_out_nt(a.outp, row0, inter, t);
}

// ================= fused grad head =================
struct GradArgs {
  const float* h; const int* se_src; const int* se_dst; const int* se_e;
  const u16* eA; const u16* bt1; const float* b1; const u16* bt2; const float* b2;
  const float* W3; const float* b3; float* outp;
};
__global__ __launch_bounds__(256, 3) void gradf_k(GradArgs a) {
  __shared__ u16 inter[64 * 256];
  const int t = threadIdx.x;
  const int w = t >> 6, lane = t & 63, m = lane & 15, quad = lane >> 4;
  const int row0 = blockIdx.x * 64;
  auto idt = [](int, int, short8 v) { return v; };
  {
    int row = t >> 2;
    int s = a.se_src[row0 + row], d = a.se_dst[row0 + row];
#pragma unroll
    for (int c = 0; c < 8; ++c) {
      int chunk = (t & 3) + c * 4, k = chunk * 8;
      const float* xp = a.h + (size_t)s * HDIM + k;
      const float* yp = a.h + (size_t)d * HDIM + k;
      float4 x0 = ld4f(xp), x1 = ld4f(xp + 4);
      float4 y0 = ld4f(yp), y1 = ld4f(yp + 4);
      short8 v;
      v[0] = (short)f2bf(x0.x * y0.x); v[1] = (short)f2bf(x0.y * y0.y);
      v[2] = (short)f2bf(x0.z * y0.z); v[3] = (short)f2bf(x0.w * y0.w);
      v[4] = (short)f2bf(x1.x * y1.x); v[5] = (short)f2bf(x1.y * y1.y);
      v[6] = (short)f2bf(x1.z * y1.z); v[7] = (short)f2bf(x1.w * y1.w);
      *(short8*)&inter[row * 256 + ((chunk ^ (row & 7)) << 3)] = v;
    }
  }
  __syncthreads();
  f32x4 acc[4][4];
  zacc(acc);
  gemm44<8, 256, 4, 0, false>(acc, a.bt1, inter, w, m, quad, idt);
  __syncthreads();
  {
    int row = t >> 2;
#pragma unroll
    for (int c = 0; c < 8; ++c) {
      int chunk = (t & 3) + c * 4;
      short8 v = __builtin_nontemporal_load((const short8*)(a.eA + (size_t)(row0 + row) * HDIM + chunk * 8));
      *(short8*)&inter[row * 256 + ((chunk ^ (row & 7)) << 3)] = v;
    }
  }
  __syncthreads();
  gemm44<8, 256, 4, 0, false>(acc, a.bt1 + 8 * 256 * 32, inter, w, m, quad, idt);  // accumulate
  __syncthreads();
  store_inter44<4, 1, 0>(inter, w, m, quad, acc, a.b1);   // relu
  __syncthreads();
  zacc(acc);
  gemm44<8, 128, 2, 0, false>(acc, a.bt2, inter, w, m, quad, idt);
  float p[4][4];
#pragma unroll
  for (int mt = 0; mt < 4; ++mt) { p[mt][0]=0.f; p[mt][1]=0.f; p[mt][2]=0.f; p[mt][3]=0.f; }
#pragma unroll
  for (int mt = 0; mt < 4; ++mt)
#pragma unroll
    for (int nt = 0; nt < 2; ++nt) {
      int col = w * 32 + nt * 16 + m;
      float w3 = a.W3[col], bv = a.b2[col];
#pragma unroll
      for (int r = 0; r < 4; ++r) p[mt][r] += fmaxf(acc[mt][nt][r] + bv, 0.f) * w3;
    }
  __syncthreads();
  float* red = (float*)inter;   // 64 x 68
#pragma unroll
  for (int mt = 0; mt < 4; ++mt)
#pragma unroll
    for (int r = 0; r < 4; ++r)
      red[(mt * 16 + quad * 4 + r) * 68 + w * 16 + m] = p[mt][r];
  __syncthreads();
  if (t < 64) {
    float s = a.b3[0];
#pragma unroll
    for (int i = 0; i < 64; ++i) s += red[t * 68 + i];
    a.outp[a.se_e[row0 + t]] = s;
  }
}

// ================= node-side =================
struct LinArgs { const float* A; const u16* bt; float* C; int M; };
__global__ __launch_bounds__(256, 3) void lin1_k(LinArgs a) {
  __shared__ u16 inter[64 * 256];
  const int t = threadIdx.x;
  const int w = t >> 6, lane = t & 63, m = lane & 15, quad = lane >> 4;
  const int row0 = blockIdx.x * 64;
  auto idt = [](int, int, short8 v) { return v; };
  {
    int row = t >> 2, grow = row0 + row;
#pragma unroll
    for (int c = 0; c < 8; ++c) {
      int chunk = (t & 3) + c * 4, k = chunk * 8;
      short8 v;
      if (grow < a.M) {
        const float* p = a.A + (size_t)grow * HDIM + k;
        float4 x0 = ld4f(p), x1 = ld4f(p + 4);
        v[0]=(short)f2bf(x0.x); v[1]=(short)f2bf(x0.y); v[2]=(short)f2bf(x0.z); v[3]=(short)f2bf(x0.w);
        v[4]=(short)f2bf(x1.x); v[5]=(short)f2bf(x1.y); v[6]=(short)f2bf(x1.z); v[7]=(short)f2bf(x1.w);
      } else { v = short8{0,0,0,0,0,0,0,0}; }
      *(short8*)&inter[row * 256 + ((chunk ^ (row & 7)) << 3)] = v;
    }
  }
  __syncthreads();
  f32x4 acc[4][4];
  zacc(acc);
  gemm44<8, 256, 4, 0, false>(acc, a.bt, inter, w, m, quad, idt);
  store_node44<4, 0, 0>(a.C, row0, w, m, quad, acc, nullptr, a.M);
}

struct Lin23Args { const float* A; const u16* bt2; const float* b2; const u16* bt3; const float* b3; float* C; int M; };
__global__ __launch_bounds__(256, 3) void lin23_k(Lin23Args a) {
  __shared__ u16 inter[64 * 256];
  const int t = threadIdx.x;
  const int w = t >> 6, lane = t & 63, m = lane & 15, quad = lane >> 4;
  const int row0 = blockIdx.x * 64;
  auto idt = [](int, int, short8 v) { return v; };
  {
    int row = t >> 2, grow = row0 + row;
#pragma unroll
    for (int c = 0; c < 8; ++c) {
      int chunk = (t & 3) + c * 4, k = chunk * 8;
      short8 v;
      if (grow < a.M) {
        const float* p = a.A + (size_t)grow * HDIM + k;
        float4 x0 = ld4f(p), x1 = ld4f(p + 4);
        v[0]=(short)f2bf(x0.x); v[1]=(short)f2bf(x0.y); v[2]=(short)f2bf(x0.z); v[3]=(short)f2bf(x0.w);
        v[4]=(short)f2bf(x1.x); v[5]=(short)f2bf(x1.y); v[6]=(short)f2bf(x1.z); v[7]=(short)f2bf(x1.w);
      } else { v = short8{0,0,0,0,0,0,0,0}; }
      *(short8*)&inter[row * 256 + ((chunk ^ (row & 7)) << 3)] = v;
    }
  }
  __syncthreads();
  f32x4 acc[4][4];
  zacc(acc);
  gemm44<8, 256, 4, 0, false>(acc, a.bt2, inter, w, m, quad, idt);
  __syncthreads();
  store_inter44<4, 2, 0>(inter, w, m, quad, acc, a.b2);   // ssp
  __syncthreads();
  zacc(acc);
  gemm44<8, 256, 4, 0, false>(acc, a.bt3, inter, w, m, quad, idt);
  store_node44<4, 0, 1>(a.C, row0, w, m, quad, acc, a.b3, a.M);  // h +=
}

// ================= weight transpose to k-step-major [kstep][n][32]; fmt 0 bf16, 1 f16 =================
struct WTDesc { const float* src; u16* dst; int K; int Nshift; int fmt; };
struct WTList { WTDesc d[35]; };
__global__ __launch_bounds__(256) void wtrans_k(WTList wl) {
  WTDesc e = wl.d[blockIdx.y];
  int total = e.K << e.Nshift;
  int idx = blockIdx.x * 256 + threadIdx.x;
  if (idx >= total) return;
  int k = idx >> e.Nshift;
  int n = idx & ((1 << e.Nshift) - 1);
  float v = e.src[idx];
  e.dst[((size_t)(k >> 5) << (e.Nshift + 5)) + n * 32 + (k & 31)] = e.fmt ? f2h_bits(v) : f2bf(v);
}

// ================= small kernels =================
__global__ void node_embed_k(const int* atom_type, const float* r_feat, const float* p_feat,
                             const float* emb, const float* fW, float* z, int N, int F) {
  int n = blockIdx.x;
  int j = threadIdx.x;  // 128
  __shared__ float rr[32], pp[32];
  if (j < F) { rr[j] = r_feat[(size_t)n * F + j]; pp[j] = p_feat[(size_t)n * F + j]; }
  __syncthreads();
  float ar = 0.f, ap = 0.f;
  for (int f = 0; f < F; ++f) {
    float wv = fW[f * 128 + j];
    ar += rr[f] * wv;
    ap += pp[f] * wv;
  }
  int at = atom_type[n];
  z[(size_t)n * HDIM + j] = emb[at * 128 + j] + ar;
  z[(size_t)n * HDIM + 128 + j] = ap - ar;
}

__global__ void edge_geom_k(const float* pos, const int* src, const int* dst, float* len_out, int E) {
  int e = blockIdx.x * blockDim.x + threadIdx.x;
  if (e >= E) return;
  int s = src[e], d = dst[e];
  float dx = pos[s * 3 + 0] - pos[d * 3 + 0];
  float dy = pos[s * 3 + 1] - pos[d * 3 + 1];
  float dz = pos[s * 3 + 2] - pos[d * 3 + 2];
  len_out[e] = sqrtf(dx * dx + dy * dy + dz * dz + 1e-12f);
}

__global__ void zero_k(float4* p, int n4) {
  int i = blockIdx.x * 256 + threadIdx.x;
  if (i < n4) p[i] = make_float4(0.f, 0.f, 0.f, 0.f);
}
__global__ void zero_int_k(int* p, int n) {
  int i = blockIdx.x * 256 + threadIdx.x;
  if (i < n) p[i] = 0;
}
__global__ void hist_k(const int* dst, int* cnt, int E) {
  int e = blockIdx.x * 256 + threadIdx.x;
  if (e < E) atomicAdd(&cnt[dst[e]], 1);
}
__global__ __launch_bounds__(256) void scan_k(const int* cnt, int* rowstart, int N) {
  __shared__ int part[256];
  int t = threadIdx.x;
  int chunk = (N + 255) / 256;
  int lo = t * chunk, hi = lo + chunk; if (hi > N) hi = N; if (lo > N) lo = N;
  int s = 0;
  for (int i = lo; i < hi; ++i) s += cnt[i];
  part[t] = s;
  __syncthreads();
  for (int off = 1; off < 256; off <<= 1) {
    int v = (t >= off) ? part[t - off] : 0;
    __syncthreads();
    part[t] += v;
    __syncthreads();
  }
  int run = (t == 0) ? 0 : part[t - 1];
  for (int i = lo; i < hi; ++i) { rowstart[i] = run; run += cnt[i]; }
  if (t == 255) rowstart[N] = run;
}
__global__ void fill_k(const int* src, const int* dst, const int* rowstart, int* cursor,
                       int* se_src, int* se_dst, int* se_e, int E) {
  int e = blockIdx.x * 256 + threadIdx.x;
  if (e >= E) return;
  int d = dst[e];
  int p = atomicAdd(&cursor[d], 1);
  int idx = rowstart[d] + p;
  se_src[idx] = src[e];
  se_dst[idx] = d;
  se_e[idx] = e;
}

__global__ __launch_bounds__(256) void gather_k(const float* hh, const u16* Wf,
                                                const int* se_src, const int* rowstart,
                                                float* agg, int N) {
  int n = blockIdx.x;
  int j = threadIdx.x;
  int s0 = rowstart[n], s1 = rowstart[n + 1];
  float acc = 0.f;
  for (int i = s0; i < s1; ++i) {
    u16 wv = __builtin_nontemporal_load(Wf + (size_t)i * HDIM + j);
    acc += hh[(size_t)se_src[i] * HDIM + j] * bf2f(wv);
  }
  agg[(size_t)n * HDIM + j] = acc;
}

extern "C" void kernel_launch(void* const* d_in, const int* in_sizes, int n_in,
                              void* d_out, int out_size, void* d_ws, size_t ws_size,
                              hipStream_t stream) {
  const int* atom_type = (const int*)d_in[0];
  const float* r_feat  = (const float*)d_in[1];
  const float* p_feat  = (const float*)d_in[2];
  const float* pos     = (const float*)d_in[3];
  const int* eidx      = (const int*)d_in[4];
  const int* etype_r   = (const int*)d_in[5];
  const int* etype_p   = (const int*)d_in[6];
  const float* atom_emb = (const float*)d_in[7];
  const float* feat_W   = (const float*)d_in[8];
  const float* bondT    = (const float*)d_in[9];
  const float* e_W1     = (const float*)d_in[10];
  const float* e_b1     = (const float*)d_in[11];
  const float* e_W2     = (const float*)d_in[12];
  const float* e_b2     = (const float*)d_in[13];
  const float* cat_W1   = (const float*)d_in[14];
  const float* cat_b1   = (const float*)d_in[15];
  const float* cat_W2   = (const float*)d_in[16];
  const float* cat_b2   = (const float*)d_in[17];
  const float* filt_W1  = (const float*)d_in[18];
  const float* filt_b1  = (const float*)d_in[19];
  const float* filt_W2  = (const float*)d_in[20];
  const float* filt_b2  = (const float*)d_in[21];
  const float* lin1_W   = (const float*)d_in[22];
  const float* lin2_W   = (const float*)d_in[23];
  const float* lin2_b   = (const float*)d_in[24];
  const float* lin3_W   = (const float*)d_in[25];
  const float* lin3_b   = (const float*)d_in[26];
  const float* grad_W1  = (const float*)d_in[27];
  const float* grad_b1  = (const float*)d_in[28];
  const float* grad_W2  = (const float*)d_in[29];
  const float* grad_b2  = (const float*)d_in[30];
  const float* grad_W3  = (const float*)d_in[31];
  const float* grad_b3  = (const float*)d_in[32];

  const int N = in_sizes[0];
  const int F = in_sizes[1] / N;
  const int E = in_sizes[4] / 2;
  const int L = in_sizes[18] / (HDIM * HDIM);
  const int* srcI = eidx;
  const int* dstI = eidx + E;
  float* out = (float*)d_out;

  const size_t BT_ELEMS = (size_t)(32 * 65536 + 2 * 131072 + 32768);
  size_t need = 2 * (size_t)E * HDIM * 2 + 3 * (size_t)N * HDIM * 4 + BT_ELEMS * 2
              + (size_t)(3 * E + 3 * N + 1) * 4 + 64;
  if (ws_size < need) {
    int n4 = (out_size + 3) / 4;
    zero_k<<<(n4 + 255) / 256, 256, 0, stream>>>((float4*)d_out, n4);
    return;
  }
  char* base = (char*)d_ws;
  u16* eA = (u16*)base; base += (size_t)E * HDIM * 2;
  u16* Wf = (u16*)base; base += (size_t)E * HDIM * 2;
  float* h   = (float*)base; base += (size_t)N * HDIM * 4;
  float* hh  = (float*)base; base += (size_t)N * HDIM * 4;
  float* agg = (float*)base; base += (size_t)N * HDIM * 4;
  u16* bt = (u16*)base; base += BT_ELEMS * 2;
  int* se_src = (int*)base; base += (size_t)E * 4;
  int* se_dst = (int*)base; base += (size_t)E * 4;
  int* se_e   = (int*)base; base += (size_t)E * 4;
  int* cnt    = (int*)base; base += (size_t)N * 4;
  int* cursor = (int*)base; base += (size_t)N * 4;
  int* rowstart = (int*)base; base += ((size_t)N + 1) * 4;

  size_t off = 0;
  u16* bt_eW2  = bt + off; off += 65536;
  u16* bt_cat1 = bt + off; off += 131072;
  u16* bt_cat2 = bt + off; off += 65536;
  u16* bt_f1[6]; u16* bt_f2[6]; u16* bt_l1[6]; u16* bt_l2[6]; u16* bt_l3[6];
  for (int l = 0; l < 6; ++l) { bt_f1[l] = bt + off; off += 65536; }
  for (int l = 0; l < 6; ++l) { bt_f2[l] = bt + off; off += 65536; }
  for (int l = 0; l < 6; ++l) { bt_l1[l] = bt + off; off += 65536; }
  for (int l = 0; l < 6; ++l) { bt_l2[l] = bt + off; off += 65536; }
  for (int l = 0; l < 6; ++l) { bt_l3[l] = bt + off; off += 65536; }
  u16* bt_g1 = bt + off; off += 131072;
  u16* bt_g2 = bt + off; off += 32768;

  WTList wl;
  int wi = 0;
  wl.d[wi++] = WTDesc{e_W2, bt_eW2, 256, 8, 0};
  wl.d[wi++] = WTDesc{cat_W1, bt_cat1, 512, 8, 1};   // f16 for the f16-MFMA phase
  wl.d[wi++] = WTDesc{cat_W2, bt_cat2, 256, 8, 0};
  for (int l = 0; l < 6; ++l) wl.d[wi++] = WTDesc{filt_W1 + (size_t)l * 65536, bt_f1[l], 256, 8, 0};
  for (int l = 0; l < 6; ++l) wl.d[wi++] = WTDesc{filt_W2 + (size_t)l * 65536, bt_f2[l], 256, 8, 0};
  for (int l = 0; l < 6; ++l) wl.d[wi++] = WTDesc{lin1_W + (size_t)l * 65536, bt_l1[l], 256, 8, 0};
  for (int l = 0; l < 6; ++l) wl.d[wi++] = WTDesc{lin2_W + (size_t)l * 65536, bt_l2[l], 256, 8, 0};
  for (int l = 0; l < 6; ++l) wl.d[wi++] = WTDesc{lin3_W + (size_t)l * 65536, bt_l3[l], 256, 8, 0};
  wl.d[wi++] = WTDesc{grad_W1, bt_g1, 512, 8, 0};
  wl.d[wi++] = WTDesc{grad_W2, bt_g2, 256, 7, 0};
  wtrans_k<<<dim3(512, 35), 256, 0, stream>>>(wl);

  const int EB = E / 64;
  const int NBK = (N + 63) / 64;
  const int EBLK = (E + 255) / 256;

  zero_int_k<<<(2 * N + 255) / 256, 256, 0, stream>>>(cnt, 2 * N);
  hist_k<<<EBLK, 256, 0, stream>>>(dstI, cnt, E);
  scan_k<<<1, 256, 0, stream>>>(cnt, rowstart, N);
  fill_k<<<EBLK, 256, 0, stream>>>(srcI, dstI, rowstart, cursor, se_src, se_dst, se_e, E);

  node_embed_k<<<N, 128, 0, stream>>>(atom_type, r_feat, p_feat, atom_emb, feat_W, h, N, F);
  edge_geom_k<<<EBLK, 256, 0, stream>>>(pos, srcI, dstI, out + E, E);

  EncArgs ea;
  ea.se_e = se_e; ea.lenp = out + E; ea.W1 = e_W1; ea.b1 = e_b1;
  ea.btA = bt_eW2; ea.bA = e_b2;
  ea.bondT = bondT; ea.etr = etype_r; ea.etp = etype_p;
  ea.btB = bt_cat1; ea.bB = cat_b1;
  ea.btC = bt_cat2; ea.bC = cat_b2;
  ea.outp = eA;
  encoder_k<<<EB, 256, 0, stream>>>(ea);

  for (int l = 0; l < L; ++l) {
    const size_t bo = (size_t)l * HDIM;
    FiltArgs fa{eA, bt_f1[l], filt_b1 + bo, bt_f2[l], filt_b2 + bo, Wf};
    filt_k<<<EB, 256, 0, stream>>>(fa);
    LinArgs la{h, bt_l1[l], hh, N};
    lin1_k<<<NBK, 256, 0, stream>>>(la);
    gather_k<<<N, 256, 0, stream>>>(hh, Wf, se_src, rowstart, agg, N);
    Lin23Args l23{agg, bt_l2[l], lin2_b + bo, bt_l3[l], lin3_b + bo, h, N};
    lin23_k<<<NBK, 256, 0, stream>>>(l23);
  }

  GradArgs ga;
  ga.h = h; ga.se_src = se_src; ga.se_dst = se_dst; ga.se_e = se_e;
  ga.eA = eA; ga.bt1 = bt_g1; ga.b1 = grad_b1; ga.bt2 = bt_g2; ga.b2 = grad_b2;
  ga.W3 = grad_W3; ga.b3 = grad_b3; ga.outp = out;
  gradf_k<<<EB, 256, 0, stream>>>(ga);
}

// Round 14
// 1614.076 us; speedup vs baseline: 1.1090x; 1.1090x over previous
//
#include <hip/hip_runtime.h>
#include <hip/hip_bf16.h>
#include <math.h>

#define HDIM 256

typedef unsigned short u16;
typedef short short8 __attribute__((ext_vector_type(8)));
typedef _Float16 f16x8 __attribute__((ext_vector_type(8)));
typedef float f32x4 __attribute__((ext_vector_type(4)));

// branch-free shifted softplus
__device__ __forceinline__ float sspf(float x) {
  const float LOG2E = 1.4426950408889634f, LN2 = 0.6931471805599453f;
  float t = exp2f(-fabsf(x) * LOG2E);
  return fmaxf(x, 0.f) + (log2f(1.f + t) - 1.f) * LN2;
}
__device__ __forceinline__ float bf2f(u16 u) {
  union { unsigned int i; float f; } x; x.i = ((unsigned int)u) << 16; return x.f;
}
__device__ __forceinline__ u16 f2bf(float f) {
  union { float f; unsigned int i; } x; x.f = f;
  unsigned int r = x.i + 0x7FFFu + ((x.i >> 16) & 1u);
  return (u16)(r >> 16);
}
__device__ __forceinline__ u16 f2h_bits(float f) {
  _Float16 h = (_Float16)f;
  return __builtin_bit_cast(unsigned short, h);
}
__device__ __forceinline__ float4 ld4f(const float* p) { return *(const float4*)p; }

// XOR-swizzled inter buffer (64 rows x 256 u16, 32 KB)
__device__ __forceinline__ int iw_idx(int row, int col) {
  return row * 256 + ((((col >> 3) ^ (row & 7)) << 3) | (col & 7));
}
__device__ __forceinline__ int ir_idx(int row, int cchunk) {
  return row * 256 + ((cchunk ^ (row & 7)) << 3);
}

template<int DT>
__device__ __forceinline__ f32x4 mma(short8 a, short8 b, f32x4 c) {
  if constexpr (DT == 0)
    return __builtin_amdgcn_mfma_f32_16x16x32_bf16(a, b, c, 0, 0, 0);
  else
    return __builtin_amdgcn_mfma_f32_16x16x32_f16(__builtin_bit_cast(f16x8, a),
                                                  __builtin_bit_cast(f16x8, b), c, 0, 0, 0);
}

__device__ __forceinline__ void zacc(f32x4 (&acc)[4][4]) {
#pragma unroll
  for (int i = 0; i < 4; ++i)
#pragma unroll
    for (int j = 0; j < 4; ++j) { acc[i][j][0]=0.f; acc[i][j][1]=0.f; acc[i][j][2]=0.f; acc[i][j][3]=0.f; }
}

// GEMM: 64 rows x (NTW*16 cols per wave), A from swizzled inter LDS, B per-lane global
// (k-step-major bt: [kstep][n][32]). Barrier-free.
template<int NSTEPS, int BT_N, int NTW, int DT, bool WRAP8, typename ATR>
__device__ __forceinline__ void gemm44(f32x4 (&acc)[4][4], const u16* __restrict__ bt,
                                       const u16* __restrict__ inter,
                                       int w, int m, int quad, ATR atr) {
  short8 bf[2][NTW];
#pragma unroll
  for (int nt = 0; nt < NTW; ++nt)
    bf[0][nt] = *(const short8*)(bt + (w * (NTW * 16) + nt * 16 + m) * 32 + quad * 8);
#pragma unroll
  for (int ks = 0; ks < NSTEPS; ++ks) {
    const int cur = ks & 1, nxt = cur ^ 1;
    if (ks + 1 < NSTEPS) {
#pragma unroll
      for (int nt = 0; nt < NTW; ++nt)
        bf[nxt][nt] = *(const short8*)(bt + (size_t)(ks + 1) * (BT_N * 32)
                                       + (w * (NTW * 16) + nt * 16 + m) * 32 + quad * 8);
    }
    int kchunk = (WRAP8 ? (ks & 7) : ks) * 4 + quad;
#pragma unroll
    for (int mt = 0; mt < 4; ++mt) {
      short8 af = *(const short8*)&inter[ir_idx(mt * 16 + m, kchunk)];
      af = atr(mt, ks, af);
#pragma unroll
      for (int nt = 0; nt < NTW; ++nt)
        acc[mt][nt] = mma<DT>(af, bf[cur][nt], acc[mt][nt]);
    }
  }
}

// epilogue -> swizzled inter. ACT: 0 none 1 relu 2 ssp. OF: 0 bf16, 1 f16
template<int NTW, int ACT, int OF>
__device__ __forceinline__ void store_inter44(u16* inter, int w, int m, int quad,
                                              const f32x4 (&acc)[4][4], const float* bias) {
#pragma unroll
  for (int mt = 0; mt < 4; ++mt)
#pragma unroll
    for (int nt = 0; nt < NTW; ++nt) {
      int col = w * (NTW * 16) + nt * 16 + m;
      float bv = bias[col];
#pragma unroll
      for (int r = 0; r < 4; ++r) {
        int row = mt * 16 + quad * 4 + r;
        float x = acc[mt][nt][r] + bv;
        if (ACT == 1) x = fmaxf(x, 0.f);
        else if (ACT == 2) x = sspf(x);
        inter[iw_idx(row, col)] = (OF == 0) ? f2bf(x) : f2h_bits(x);
      }
    }
}

// coalesced copy-out: swizzled inter -> global rows (contiguous 512B per row)
__device__ __forceinline__ void copy_out(u16* C, int row0, const u16* inter, int t) {
#pragma unroll
  for (int c = 0; c < 8; ++c) {
    int idx = c * 256 + t;
    int row = idx >> 5, c8 = idx & 31;
    int src = (c8 ^ (row & 7)) << 3;
    *(short8*)(C + (size_t)(row0 + row) * HDIM + c8 * 8) = *(const short8*)&inter[row * 256 + src];
  }
}

template<int NTW, int ACT, int CM>
__device__ __forceinline__ void store_node44(float* C, int row0, int w, int m, int quad,
                                             const f32x4 (&acc)[4][4], const float* bias, int M) {
#pragma unroll
  for (int mt = 0; mt < 4; ++mt)
#pragma unroll
    for (int nt = 0; nt < NTW; ++nt) {
      int col = w * (NTW * 16) + nt * 16 + m;
      float bv = bias ? bias[col] : 0.f;
#pragma unroll
      for (int r = 0; r < 4; ++r) {
        int row = row0 + mt * 16 + quad * 4 + r;
        if (row < M) {
          float x = acc[mt][nt][r] + bv;
          if (ACT == 2) x = sspf(x);
          size_t idx = (size_t)row * HDIM + col;
          if (CM == 1) x += C[idx];
          C[idx] = x;
        }
      }
    }
}

// ================= fused edge encoder =================
struct EncArgs {
  const int* se_e; const float* lenp; const float* W1; const float* b1;
  const u16* btA; const float* bA;
  const float* bondT; const int* etr; const int* etp;
  const u16* btB; const float* bB;
  const u16* btC; const float* bC;
  u16* outp;
};
__global__ __launch_bounds__(256, 3) void encoder_k(EncArgs a) {
  __shared__ u16 inter[64 * 256];
  __shared__ u16 bondL[24 * 264];
  const int t = threadIdx.x;
  const int w = t >> 6, lane = t & 63, m = lane & 15, quad = lane >> 4;
  const int row0 = blockIdx.x * 64;
  auto idt = [](int, int, short8 v) { return v; };

  for (int i = t; i < 24 * 256; i += 256) {
    int r = i >> 8, c = i & 255;
    bondL[r * 264 + c] = f2h_bits(a.bondT[r * 256 + c]);
  }
  int brv[4], bpv[4];
#pragma unroll
  for (int mt = 0; mt < 4; ++mt) {
    int eo = a.se_e[row0 + mt * 16 + m];
    brv[mt] = a.etr[eo]; bpv[mt] = a.etp[eo];
  }
  // pre-pass A: inter = ssp(len*W1+b1) bf16
  {
    int row = t >> 2;
    float len = a.lenp[a.se_e[row0 + row]];
#pragma unroll
    for (int c = 0; c < 8; ++c) {
      int chunk = (t & 3) + c * 4, k = chunk * 8;
      float4 w0 = ld4f(a.W1 + k), w1 = ld4f(a.W1 + k + 4);
      float4 c0 = ld4f(a.b1 + k), c1 = ld4f(a.b1 + k + 4);
      short8 v;
      v[0] = (short)f2bf(sspf(len * w0.x + c0.x)); v[1] = (short)f2bf(sspf(len * w0.y + c0.y));
      v[2] = (short)f2bf(sspf(len * w0.z + c0.z)); v[3] = (short)f2bf(sspf(len * w0.w + c0.w));
      v[4] = (short)f2bf(sspf(len * w1.x + c1.x)); v[5] = (short)f2bf(sspf(len * w1.y + c1.y));
      v[6] = (short)f2bf(sspf(len * w1.z + c1.z)); v[7] = (short)f2bf(sspf(len * w1.w + c1.w));
      *(short8*)&inter[row * 256 + ((chunk ^ (row & 7)) << 3)] = v;
    }
  }
  __syncthreads();
  f32x4 acc[4][4];
  zacc(acc);
  gemm44<8, 256, 4, 0, false>(acc, a.btA, inter, w, m, quad, idt);
  __syncthreads();
  store_inter44<4, 0, 1>(inter, w, m, quad, acc, a.bA);   // d_emb as f16
  __syncthreads();
  zacc(acc);
  auto atrB = [&](int mt, int ks, short8 v) -> short8 {
    int k2 = (ks & 7) * 32 + quad * 8;
    int et = (ks < 8) ? brv[mt] : bpv[mt];
    f16x8 dv = __builtin_bit_cast(f16x8, v);
    f16x8 bd = __builtin_bit_cast(f16x8, *(const short8*)&bondL[et * 264 + k2]);
    return __builtin_bit_cast(short8, dv * bd);
  };
  gemm44<16, 256, 4, 1, true>(acc, a.btB, inter, w, m, quad, atrB);
  __syncthreads();
  store_inter44<4, 1, 0>(inter, w, m, quad, acc, a.bB);   // relu, bf16
  __syncthreads();
  zacc(acc);
  gemm44<8, 256, 4, 0, false>(acc, a.btC, inter, w, m, quad, idt);
  __syncthreads();                                        // inter reads done
  store_inter44<4, 0, 0>(inter, w, m, quad, acc, a.bC);
  __syncthreads();
  copy_out(a.outp, row0, inter, t);
}

// ================= fused [filter net || lin1] (independent work, one dispatch) =================
struct FL1Args {
  // filt: Wf = ssp(eA@W1+b1)@W2+b2
  const u16* eA; const u16* bt1; const float* b1; const u16* bt2; const float* b2; u16* Wf;
  int EBlocks;
  // lin1: hh = h @ l1 (bf16 in-loader, fp32 out)
  const float* h; const u16* btL; float* hh; int M;
};
__global__ __launch_bounds__(256, 3) void fl1_k(FL1Args a) {
  __shared__ u16 inter[64 * 256];
  const int t = threadIdx.x;
  const int w = t >> 6, lane = t & 63, m = lane & 15, quad = lane >> 4;
  auto idt = [](int, int, short8 v) { return v; };
  if ((int)blockIdx.x < a.EBlocks) {
    // ---- filt path ----
    const int row0 = blockIdx.x * 64;
    {
      int row = t >> 2;
#pragma unroll
      for (int c = 0; c < 8; ++c) {
        int chunk = (t & 3) + c * 4;
        short8 v = *(const short8*)(a.eA + (size_t)(row0 + row) * HDIM + chunk * 8);
        *(short8*)&inter[row * 256 + ((chunk ^ (row & 7)) << 3)] = v;
      }
    }
    __syncthreads();
    f32x4 acc[4][4];
    zacc(acc);
    gemm44<8, 256, 4, 0, false>(acc, a.bt1, inter, w, m, quad, idt);
    __syncthreads();
    store_inter44<4, 2, 0>(inter, w, m, quad, acc, a.b1);   // ssp
    __syncthreads();
    zacc(acc);
    gemm44<8, 256, 4, 0, false>(acc, a.bt2, inter, w, m, quad, idt);
    __syncthreads();
    store_inter44<4, 0, 0>(inter, w, m, quad, acc, a.b2);
    __syncthreads();
    copy_out(a.Wf, row0, inter, t);
  } else {
    // ---- lin1 path ----
    const int row0 = ((int)blockIdx.x - a.EBlocks) * 64;
    {
      int row = t >> 2, grow = row0 + row;
#pragma unroll
      for (int c = 0; c < 8; ++c) {
        int chunk = (t & 3) + c * 4, k = chunk * 8;
        short8 v;
        if (grow < a.M) {
          const float* p = a.h + (size_t)grow * HDIM + k;
          float4 x0 = ld4f(p), x1 = ld4f(p + 4);
          v[0]=(short)f2bf(x0.x); v[1]=(short)f2bf(x0.y); v[2]=(short)f2bf(x0.z); v[3]=(short)f2bf(x0.w);
          v[4]=(short)f2bf(x1.x); v[5]=(short)f2bf(x1.y); v[6]=(short)f2bf(x1.z); v[7]=(short)f2bf(x1.w);
        } else { v = short8{0,0,0,0,0,0,0,0}; }
        *(short8*)&inter[row * 256 + ((chunk ^ (row & 7)) << 3)] = v;
      }
    }
    __syncthreads();
    f32x4 acc[4][4];
    zacc(acc);
    gemm44<8, 256, 4, 0, false>(acc, a.btL, inter, w, m, quad, idt);
    store_node44<4, 0, 0>(a.hh, row0, w, m, quad, acc, nullptr, a.M);
  }
}

// ================= fused grad head =================
struct GradArgs {
  const float* h; const int* se_src; const int* se_dst; const int* se_e;
  const u16* eA; const u16* bt1; const float* b1; const u16* bt2; const float* b2;
  const float* W3; const float* b3; float* outp;
};
__global__ __launch_bounds__(256, 3) void gradf_k(GradArgs a) {
  __shared__ u16 inter[64 * 256];
  const int t = threadIdx.x;
  const int w = t >> 6, lane = t & 63, m = lane & 15, quad = lane >> 4;
  const int row0 = blockIdx.x * 64;
  auto idt = [](int, int, short8 v) { return v; };
  {
    int row = t >> 2;
    int s = a.se_src[row0 + row], d = a.se_dst[row0 + row];
#pragma unroll
    for (int c = 0; c < 8; ++c) {
      int chunk = (t & 3) + c * 4, k = chunk * 8;
      const float* xp = a.h + (size_t)s * HDIM + k;
      const float* yp = a.h + (size_t)d * HDIM + k;
      float4 x0 = ld4f(xp), x1 = ld4f(xp + 4);
      float4 y0 = ld4f(yp), y1 = ld4f(yp + 4);
      short8 v;
      v[0] = (short)f2bf(x0.x * y0.x); v[1] = (short)f2bf(x0.y * y0.y);
      v[2] = (short)f2bf(x0.z * y0.z); v[3] = (short)f2bf(x0.w * y0.w);
      v[4] = (short)f2bf(x1.x * y1.x); v[5] = (short)f2bf(x1.y * y1.y);
      v[6] = (short)f2bf(x1.z * y1.z); v[7] = (short)f2bf(x1.w * y1.w);
      *(short8*)&inter[row * 256 + ((chunk ^ (row & 7)) << 3)] = v;
    }
  }
  __syncthreads();
  f32x4 acc[4][4];
  zacc(acc);
  gemm44<8, 256, 4, 0, false>(acc, a.bt1, inter, w, m, quad, idt);
  __syncthreads();
  {
    int row = t >> 2;
#pragma unroll
    for (int c = 0; c < 8; ++c) {
      int chunk = (t & 3) + c * 4;
      short8 v = *(const short8*)(a.eA + (size_t)(row0 + row) * HDIM + chunk * 8);
      *(short8*)&inter[row * 256 + ((chunk ^ (row & 7)) << 3)] = v;
    }
  }
  __syncthreads();
  gemm44<8, 256, 4, 0, false>(acc, a.bt1 + 8 * 256 * 32, inter, w, m, quad, idt);  // accumulate
  __syncthreads();
  store_inter44<4, 1, 0>(inter, w, m, quad, acc, a.b1);   // relu
  __syncthreads();
  zacc(acc);
  gemm44<8, 128, 2, 0, false>(acc, a.bt2, inter, w, m, quad, idt);
  float p[4][4];
#pragma unroll
  for (int mt = 0; mt < 4; ++mt) { p[mt][0]=0.f; p[mt][1]=0.f; p[mt][2]=0.f; p[mt][3]=0.f; }
#pragma unroll
  for (int mt = 0; mt < 4; ++mt)
#pragma unroll
    for (int nt = 0; nt < 2; ++nt) {
      int col = w * 32 + nt * 16 + m;
      float w3 = a.W3[col], bv = a.b2[col];
#pragma unroll
      for (int r = 0; r < 4; ++r) p[mt][r] += fmaxf(acc[mt][nt][r] + bv, 0.f) * w3;
    }
  __syncthreads();
  float* red = (float*)inter;   // 64 x 68
#pragma unroll
  for (int mt = 0; mt < 4; ++mt)
#pragma unroll
    for (int r = 0; r < 4; ++r)
      red[(mt * 16 + quad * 4 + r) * 68 + w * 16 + m] = p[mt][r];
  __syncthreads();
  if (t < 64) {
    float s = a.b3[0];
#pragma unroll
    for (int i = 0; i < 64; ++i) s += red[t * 68 + i];
    a.outp[a.se_e[row0 + t]] = s;
  }
}

// ================= lin2+lin3 fused node kernel =================
struct Lin23Args { const float* A; const u16* bt2; const float* b2; const u16* bt3; const float* b3; float* C; int M; };
__global__ __launch_bounds__(256, 3) void lin23_k(Lin23Args a) {
  __shared__ u16 inter[64 * 256];
  const int t = threadIdx.x;
  const int w = t >> 6, lane = t & 63, m = lane & 15, quad = lane >> 4;
  const int row0 = blockIdx.x * 64;
  auto idt = [](int, int, short8 v) { return v; };
  {
    int row = t >> 2, grow = row0 + row;
#pragma unroll
    for (int c = 0; c < 8; ++c) {
      int chunk = (t & 3) + c * 4, k = chunk * 8;
      short8 v;
      if (grow < a.M) {
        const float* p = a.A + (size_t)grow * HDIM + k;
        float4 x0 = ld4f(p), x1 = ld4f(p + 4);
        v[0]=(short)f2bf(x0.x); v[1]=(short)f2bf(x0.y); v[2]=(short)f2bf(x0.z); v[3]=(short)f2bf(x0.w);
        v[4]=(short)f2bf(x1.x); v[5]=(short)f2bf(x1.y); v[6]=(short)f2bf(x1.z); v[7]=(short)f2bf(x1.w);
      } else { v = short8{0,0,0,0,0,0,0,0}; }
      *(short8*)&inter[row * 256 + ((chunk ^ (row & 7)) << 3)] = v;
    }
  }
  __syncthreads();
  f32x4 acc[4][4];
  zacc(acc);
  gemm44<8, 256, 4, 0, false>(acc, a.bt2, inter, w, m, quad, idt);
  __syncthreads();
  store_inter44<4, 2, 0>(inter, w, m, quad, acc, a.b2);   // ssp
  __syncthreads();
  zacc(acc);
  gemm44<8, 256, 4, 0, false>(acc, a.bt3, inter, w, m, quad, idt);
  store_node44<4, 0, 1>(a.C, row0, w, m, quad, acc, a.b3, a.M);  // h +=
}

// ================= weight transpose to k-step-major [kstep][n][32]; fmt 0 bf16, 1 f16 =================
struct WTDesc { const float* src; u16* dst; int K; int Nshift; int fmt; };
struct WTList { WTDesc d[35]; };
__global__ __launch_bounds__(256) void wtrans_k(WTList wl) {
  WTDesc e = wl.d[blockIdx.y];
  int total = e.K << e.Nshift;
  int idx = blockIdx.x * 256 + threadIdx.x;
  if (idx >= total) return;
  int k = idx >> e.Nshift;
  int n = idx & ((1 << e.Nshift) - 1);
  float v = e.src[idx];
  e.dst[((size_t)(k >> 5) << (e.Nshift + 5)) + n * 32 + (k & 31)] = e.fmt ? f2h_bits(v) : f2bf(v);
}

// ================= small kernels =================
__global__ void node_embed_k(const int* atom_type, const float* r_feat, const float* p_feat,
                             const float* emb, const float* fW, float* z, int N, int F) {
  int n = blockIdx.x;
  int j = threadIdx.x;  // 128
  __shared__ float rr[32], pp[32];
  if (j < F) { rr[j] = r_feat[(size_t)n * F + j]; pp[j] = p_feat[(size_t)n * F + j]; }
  __syncthreads();
  float ar = 0.f, ap = 0.f;
  for (int f = 0; f < F; ++f) {
    float wv = fW[f * 128 + j];
    ar += rr[f] * wv;
    ap += pp[f] * wv;
  }
  int at = atom_type[n];
  z[(size_t)n * HDIM + j] = emb[at * 128 + j] + ar;
  z[(size_t)n * HDIM + 128 + j] = ap - ar;
}

__global__ void edge_geom_k(const float* pos, const int* src, const int* dst, float* len_out, int E) {
  int e = blockIdx.x * blockDim.x + threadIdx.x;
  if (e >= E) return;
  int s = src[e], d = dst[e];
  float dx = pos[s * 3 + 0] - pos[d * 3 + 0];
  float dy = pos[s * 3 + 1] - pos[d * 3 + 1];
  float dz = pos[s * 3 + 2] - pos[d * 3 + 2];
  len_out[e] = sqrtf(dx * dx + dy * dy + dz * dz + 1e-12f);
}

__global__ void zero_k(float4* p, int n4) {
  int i = blockIdx.x * 256 + threadIdx.x;
  if (i < n4) p[i] = make_float4(0.f, 0.f, 0.f, 0.f);
}
__global__ void zero_int_k(int* p, int n) {
  int i = blockIdx.x * 256 + threadIdx.x;
  if (i < n) p[i] = 0;
}
__global__ void hist_k(const int* dst, int* cnt, int E) {
  int e = blockIdx.x * 256 + threadIdx.x;
  if (e < E) atomicAdd(&cnt[dst[e]], 1);
}
__global__ __launch_bounds__(256) void scan_k(const int* cnt, int* rowstart, int N) {
  __shared__ int part[256];
  int t = threadIdx.x;
  int chunk = (N + 255) / 256;
  int lo = t * chunk, hi = lo + chunk; if (hi > N) hi = N; if (lo > N) lo = N;
  int s = 0;
  for (int i = lo; i < hi; ++i) s += cnt[i];
  part[t] = s;
  __syncthreads();
  for (int off = 1; off < 256; off <<= 1) {
    int v = (t >= off) ? part[t - off] : 0;
    __syncthreads();
    part[t] += v;
    __syncthreads();
  }
  int run = (t == 0) ? 0 : part[t - 1];
  for (int i = lo; i < hi; ++i) { rowstart[i] = run; run += cnt[i]; }
  if (t == 255) rowstart[N] = run;
}
__global__ void fill_k(const int* src, const int* dst, const int* rowstart, int* cursor,
                       int* se_src, int* se_dst, int* se_e, int E) {
  int e = blockIdx.x * 256 + threadIdx.x;
  if (e >= E) return;
  int d = dst[e];
  int p = atomicAdd(&cursor[d], 1);
  int idx = rowstart[d] + p;
  se_src[idx] = src[e];
  se_dst[idx] = d;
  se_e[idx] = e;
}

__global__ __launch_bounds__(256) void gather_k(const float* hh, const u16* Wf,
                                                const int* se_src, const int* rowstart,
                                                float* agg, int N) {
  int n = blockIdx.x;
  int j = threadIdx.x;
  int s0 = rowstart[n], s1 = rowstart[n + 1];
  float acc = 0.f;
  for (int i = s0; i < s1; ++i)
    acc += hh[(size_t)se_src[i] * HDIM + j] * bf2f(Wf[(size_t)i * HDIM + j]);
  agg[(size_t)n * HDIM + j] = acc;
}

extern "C" void kernel_launch(void* const* d_in, const int* in_sizes, int n_in,
                              void* d_out, int out_size, void* d_ws, size_t ws_size,
                              hipStream_t stream) {
  const int* atom_type = (const int*)d_in[0];
  const float* r_feat  = (const float*)d_in[1];
  const float* p_feat  = (const float*)d_in[2];
  const float* pos     = (const float*)d_in[3];
  const int* eidx      = (const int*)d_in[4];
  const int* etype_r   = (const int*)d_in[5];
  const int* etype_p   = (const int*)d_in[6];
  const float* atom_emb = (const float*)d_in[7];
  const float* feat_W   = (const float*)d_in[8];
  const float* bondT    = (const float*)d_in[9];
  const float* e_W1     = (const float*)d_in[10];
  const float* e_b1     = (const float*)d_in[11];
  const float* e_W2     = (const float*)d_in[12];
  const float* e_b2     = (const float*)d_in[13];
  const float* cat_W1   = (const float*)d_in[14];
  const float* cat_b1   = (const float*)d_in[15];
  const float* cat_W2   = (const float*)d_in[16];
  const float* cat_b2   = (const float*)d_in[17];
  const float* filt_W1  = (const float*)d_in[18];
  const float* filt_b1  = (const float*)d_in[19];
  const float* filt_W2  = (const float*)d_in[20];
  const float* filt_b2  = (const float*)d_in[21];
  const float* lin1_W   = (const float*)d_in[22];
  const float* lin2_W   = (const float*)d_in[23];
  const float* lin2_b   = (const float*)d_in[24];
  const float* lin3_W   = (const float*)d_in[25];
  const float* lin3_b   = (const float*)d_in[26];
  const float* grad_W1  = (const float*)d_in[27];
  const float* grad_b1  = (const float*)d_in[28];
  const float* grad_W2  = (const float*)d_in[29];
  const float* grad_b2  = (const float*)d_in[30];
  const float* grad_W3  = (const float*)d_in[31];
  const float* grad_b3  = (const float*)d_in[32];

  const int N = in_sizes[0];
  const int F = in_sizes[1] / N;
  const int E = in_sizes[4] / 2;
  const int L = in_sizes[18] / (HDIM * HDIM);
  const int* srcI = eidx;
  const int* dstI = eidx + E;
  float* out = (float*)d_out;

  const size_t BT_ELEMS = (size_t)(32 * 65536 + 2 * 131072 + 32768);
  size_t need = 2 * (size_t)E * HDIM * 2 + 3 * (size_t)N * HDIM * 4 + BT_ELEMS * 2
              + (size_t)(3 * E + 3 * N + 1) * 4 + 64;
  if (ws_size < need) {
    int n4 = (out_size + 3) / 4;
    zero_k<<<(n4 + 255) / 256, 256, 0, stream>>>((float4*)d_out, n4);
    return;
  }
  char* base = (char*)d_ws;
  u16* eA = (u16*)base; base += (size_t)E * HDIM * 2;
  u16* Wf = (u16*)base; base += (size_t)E * HDIM * 2;
  float* h   = (float*)base; base += (size_t)N * HDIM * 4;
  float* hh  = (float*)base; base += (size_t)N * HDIM * 4;
  float* agg = (float*)base; base += (size_t)N * HDIM * 4;
  u16* bt = (u16*)base; base += BT_ELEMS * 2;
  int* se_src = (int*)base; base += (size_t)E * 4;
  int* se_dst = (int*)base; base += (size_t)E * 4;
  int* se_e   = (int*)base; base += (size_t)E * 4;
  int* cnt    = (int*)base; base += (size_t)N * 4;
  int* cursor = (int*)base; base += (size_t)N * 4;
  int* rowstart = (int*)base; base += ((size_t)N + 1) * 4;

  size_t off = 0;
  u16* bt_eW2  = bt + off; off += 65536;
  u16* bt_cat1 = bt + off; off += 131072;
  u16* bt_cat2 = bt + off; off += 65536;
  u16* bt_f1[6]; u16* bt_f2[6]; u16* bt_l1[6]; u16* bt_l2[6]; u16* bt_l3[6];
  for (int l = 0; l < 6; ++l) { bt_f1[l] = bt + off; off += 65536; }
  for (int l = 0; l < 6; ++l) { bt_f2[l] = bt + off; off += 65536; }
  for (int l = 0; l < 6; ++l) { bt_l1[l] = bt + off; off += 65536; }
  for (int l = 0; l < 6; ++l) { bt_l2[l] = bt + off; off += 65536; }
  for (int l = 0; l < 6; ++l) { bt_l3[l] = bt + off; off += 65536; }
  u16* bt_g1 = bt + off; off += 131072;
  u16* bt_g2 = bt + off; off += 32768;

  WTList wl;
  int wi = 0;
  wl.d[wi++] = WTDesc{e_W2, bt_eW2, 256, 8, 0};
  wl.d[wi++] = WTDesc{cat_W1, bt_cat1, 512, 8, 1};   // f16 for the f16-MFMA phase
  wl.d[wi++] = WTDesc{cat_W2, bt_cat2, 256, 8, 0};
  for (int l = 0; l < 6; ++l) wl.d[wi++] = WTDesc{filt_W1 + (size_t)l * 65536, bt_f1[l], 256, 8, 0};
  for (int l = 0; l < 6; ++l) wl.d[wi++] = WTDesc{filt_W2 + (size_t)l * 65536, bt_f2[l], 256, 8, 0};
  for (int l = 0; l < 6; ++l) wl.d[wi++] = WTDesc{lin1_W + (size_t)l * 65536, bt_l1[l], 256, 8, 0};
  for (int l = 0; l < 6; ++l) wl.d[wi++] = WTDesc{lin2_W + (size_t)l * 65536, bt_l2[l], 256, 8, 0};
  for (int l = 0; l < 6; ++l) wl.d[wi++] = WTDesc{lin3_W + (size_t)l * 65536, bt_l3[l], 256, 8, 0};
  wl.d[wi++] = WTDesc{grad_W1, bt_g1, 512, 8, 0};
  wl.d[wi++] = WTDesc{grad_W2, bt_g2, 256, 7, 0};
  wtrans_k<<<dim3(512, 35), 256, 0, stream>>>(wl);

  const int EB = E / 64;
  const int NBK = (N + 63) / 64;
  const int EBLK = (E + 255) / 256;

  zero_int_k<<<(2 * N + 255) / 256, 256, 0, stream>>>(cnt, 2 * N);
  hist_k<<<EBLK, 256, 0, stream>>>(dstI, cnt, E);
  scan_k<<<1, 256, 0, stream>>>(cnt, rowstart, N);
  fill_k<<<EBLK, 256, 0, stream>>>(srcI, dstI, rowstart, cursor, se_src, se_dst, se_e, E);

  node_embed_k<<<N, 128, 0, stream>>>(atom_type, r_feat, p_feat, atom_emb, feat_W, h, N, F);
  edge_geom_k<<<EBLK, 256, 0, stream>>>(pos, srcI, dstI, out + E, E);

  EncArgs ea;
  ea.se_e = se_e; ea.lenp = out + E; ea.W1 = e_W1; ea.b1 = e_b1;
  ea.btA = bt_eW2; ea.bA = e_b2;
  ea.bondT = bondT; ea.etr = etype_r; ea.etp = etype_p;
  ea.btB = bt_cat1; ea.bB = cat_b1;
  ea.btC = bt_cat2; ea.bC = cat_b2;
  ea.outp = eA;
  encoder_k<<<EB, 256, 0, stream>>>(ea);

  for (int l = 0; l < L; ++l) {
    const size_t bo = (size_t)l * HDIM;
    FL1Args fl;
    fl.eA = eA; fl.bt1 = bt_f1[l]; fl.b1 = filt_b1 + bo; fl.bt2 = bt_f2[l]; fl.b2 = filt_b2 + bo;
    fl.Wf = Wf; fl.EBlocks = EB;
    fl.h = h; fl.btL = bt_l1[l]; fl.hh = hh; fl.M = N;
    fl1_k<<<EB + NBK, 256, 0, stream>>>(fl);
    gather_k<<<N, 256, 0, stream>>>(hh, Wf, se_src, rowstart, agg, N);
    Lin23Args l23{agg, bt_l2[l], lin2_b + bo, bt_l3[l], lin3_b + bo, h, N};
    lin23_k<<<NBK, 256, 0, stream>>>(l23);
  }

  GradArgs ga;
  ga.h = h; ga.se_src = se_src; ga.se_dst = se_dst; ga.se_e = se_e;
  ga.eA = eA; ga.bt1 = bt_g1; ga.b1 = grad_b1; ga.bt2 = bt_g2; ga.b2 = grad_b2;
  ga.W3 = grad_W3; ga.b3 = grad_b3; ga.outp = out;
  gradf_k<<<EB, 256, 0, stream>>>(ga);
}